// Round 10
// baseline (366.958 us; speedup 1.0000x reference)
//
#include <hip/hip_runtime.h>
#include <cstddef>
#include <cstdint>

// ---------------------------------------------------------------------------
// SO2_Linear r7 (resubmit 3, audited x5): rotate_gather fused into GEMM.
//   1. wigner_k   : per-edge D1 (3x3), D2 (5x5) -> ws (f32)
//   2. build_mats : W0/W1/W2 -> fp16 M0(384x256), M1(512x512), M2(256x256)
//   3. rg_gemm    : per 64-edge block: phase1 rotates x -> swizzled LDS A-panel
//                   (64x1024 f16, full K resident); phase2 runs 9 section-jobs
//                   (B tile staged from L2 per kk), epilogue -> packed V fp16
//   4. rotate_back2: thread-per-(edge,channel), V(f16) -> D-rotated f32 out
// ---------------------------------------------------------------------------

typedef _Float16 f16x8 __attribute__((ext_vector_type(8)));
typedef _Float16 f16x2 __attribute__((ext_vector_type(2)));
typedef float    f32x4 __attribute__((ext_vector_type(4)));

#define AS1 __attribute__((address_space(1)))
#define AS3 __attribute__((address_space(3)))

__device__ __forceinline__ void mm3(const float* A, const float* B, float* C) {
#pragma unroll
  for (int i = 0; i < 3; ++i)
#pragma unroll
    for (int j = 0; j < 3; ++j)
      C[i*3+j] = fmaf(A[i*3+0], B[0*3+j], fmaf(A[i*3+1], B[1*3+j], A[i*3+2]*B[2*3+j]));
}

__device__ __forceinline__ void mm5(const float* A, const float* B, float* C) {
#pragma unroll
  for (int i = 0; i < 5; ++i)
#pragma unroll
    for (int j = 0; j < 5; ++j) {
      float s = 0.f;
#pragma unroll
      for (int k = 0; k < 5; ++k) s = fmaf(A[i*5+k], B[k*5+j], s);
      C[i*5+j] = s;
    }
}

__global__ __launch_bounds__(256) void wigner_k(const float* __restrict__ R,
                                                float* __restrict__ D1buf,
                                                float* __restrict__ D2buf, int n) {
  int e = blockIdx.x*256 + threadIdx.x;
  if (e >= n) return;
  float r0 = R[3*e+0], r1 = R[3*e+1], r2 = R[3*e+2];
  float v0 = r1, v1 = r2, v2 = r0;          // v = R[[1,2,0]]
  float nrm = fmaxf(sqrtf(v0*v0 + v1*v1 + v2*v2), 1e-12f);
  float inv = 1.0f/nrm;
  v0 *= inv; v1 *= inv; v2 *= inv;

  float cb = fminf(fmaxf(v1, -1.f), 1.f);
  float sb = sqrtf(fmaxf(1.f - cb*cb, 0.f));
  float h = sqrtf(v0*v0 + v2*v2);
  float ca, sa;
  if (h > 1e-20f) { float ih = 1.f/h; ca = v2*ih; sa = v0*ih; }
  else            { ca = 1.f; sa = 0.f; }

  {
    float Za[9] = {ca,0,sa, 0,1,0, -sa,0,ca};
    float Zb[9] = {cb,0,sb, 0,1,0, -sb,0,cb};
    const float J1[9] = {0,1,0, 1,0,0, 0,0,-1};
    float T[9], T2[9], D1[9];
    mm3(Zb, J1, T); mm3(J1, T, T2); mm3(Za, T2, D1);
#pragma unroll
    for (int i = 0; i < 9; ++i) D1buf[(size_t)e*9 + i] = D1[i];
  }
  {
    float c2a = ca*ca - sa*sa, s2a = 2.f*ca*sa;
    float c2b = cb*cb - sb*sb, s2b = 2.f*cb*sb;
    float Za2[25] = {
      c2a, 0,   0, 0,   s2a,
      0,   ca,  0, sa,  0,
      0,   0,   1, 0,   0,
      0,  -sa,  0, ca,  0,
     -s2a, 0,   0, 0,   c2a};
    float Zb2[25] = {
      c2b, 0,   0, 0,   s2b,
      0,   cb,  0, sb,  0,
      0,   0,   1, 0,   0,
      0,  -sb,  0, cb,  0,
     -s2b, 0,   0, 0,   c2b};
    const float S3 = 0.8660254037844386f;
    const float J2[25] = {
      0, 0, 0,    -1, 0,
      0, 1, 0,     0, 0,
      0, 0, -0.5f, 0, -S3,
     -1, 0, 0,     0, 0,
      0, 0, -S3,   0, 0.5f};
    float T[25], T2[25], D2[25];
    mm5(Zb2, J2, T); mm5(J2, T, T2); mm5(Za2, T2, D2);
#pragma unroll
    for (int i = 0; i < 25; ++i) D2buf[(size_t)e*25 + i] = D2[i];
  }
}

__global__ __launch_bounds__(256) void build_mats(const float* __restrict__ W0,
                                                  const float* __restrict__ b0,
                                                  const float* __restrict__ W1,
                                                  const float* __restrict__ W2,
                                                  _Float16* __restrict__ M0,
                                                  float* __restrict__ B0,
                                                  _Float16* __restrict__ M1,
                                                  _Float16* __restrict__ M2) {
  int i = blockIdx.x*256 + threadIdx.x;
  if (i < 98304) {                       // M0: 384 x 256 = W0[:,128:384]
    int k = i >> 8, j = i & 255;
    M0[i] = (_Float16)W0[k*384 + 128 + j];
  } else if (i < 98688) {                // B0: 384 (f32)
    B0[i - 98304] = b0[i - 98304];
  } else if (i < 360832) {               // M1: 512 x 512 = [[Wa,-Wb],[Wb,Wa]]
    int idx = i - 98688;
    int k = idx >> 9, j = idx & 511;
    float val;
    if (k < 256) val = (j < 256) ? W1[k*256 + j] : -W1[(k+256)*256 + (j-256)];
    else         val = (j < 256) ? W1[k*256 + j] :  W1[(k-256)*256 + (j-256)];
    M1[idx] = (_Float16)val;
  } else if (i < 426368) {               // M2: 256 x 256 = [[Wa,-Wb],[Wb,Wa]]
    int idx = i - 360832;
    int k = idx >> 8, j = idx & 255;
    float val;
    if (k < 128) val = (j < 128) ? W2[k*128 + j] : -W2[(k+128)*128 + (j-128)];
    else         val = (j < 128) ? W2[k*128 + j] :  W2[(k-128)*128 + (j-128)];
    M2[idx] = (_Float16)val;
  }
}

// Fused: rotate x into swizzled LDS A-panel (64 edges x 1024 cols, f16), then
// 9 GEMM section-jobs against it, output packed V fp16 to global.
// LDS: Uls 128 KB + Bls 16 KB = 144 KB -> 1 block/CU, 8 waves.
__global__ __launch_bounds__(512) void rg_gemm(const float* __restrict__ x,
                                               const float* __restrict__ D1buf,
                                               const float* __restrict__ D2buf,
                                               const _Float16* __restrict__ M0,
                                               const float* __restrict__ B0,
                                               const _Float16* __restrict__ M1,
                                               const _Float16* __restrict__ M2,
                                               _Float16* __restrict__ C, int n) {
  __shared__ __align__(16) _Float16 Uls[64*1024];  // [edge][col], seg-swizzled
  __shared__ __align__(16) _Float16 Bls[128*64];   // [col][64K],  seg-swizzled

  const int t = threadIdx.x;
  const int rowBase = blockIdx.x * 64;

  // ---- phase 1: rotate 64 edges of x -> Uls ----
  // U col v of edge el at byte: el*2048 + (((v>>3) ^ (el&7))<<4) + ((v&7)<<1)
  {
    const int elo = t >> 7;        // wave-uniform (0..3)
    const int c   = t & 127;
#pragma unroll 1
    for (int it = 0; it < 16; ++it) {
      const int el = it*4 + elo;
      const int e  = rowBase + el;
      float d1[9], d2[25];
#pragma unroll
      for (int i = 0; i < 9; ++i)  d1[i] = D1buf[(size_t)e*9 + i];
#pragma unroll
      for (int i = 0; i < 25; ++i) d2[i] = D2buf[(size_t)e*25 + i];
      const float* xr = x + (size_t)e*1152;

      // l=1: r = D1^T b
      float b0 = xr[128 + 3*c + 0];
      float b1 = xr[128 + 3*c + 1];
      float b2 = xr[128 + 3*c + 2];
      float r0 = fmaf(d1[0], b0, fmaf(d1[3], b1, d1[6]*b2));
      float r1 = fmaf(d1[1], b0, fmaf(d1[4], b1, d1[7]*b2));
      float r2 = fmaf(d1[2], b0, fmaf(d1[5], b1, d1[8]*b2));
      // l=2: rr = D2^T q
      float q0 = xr[512 + 5*c + 0];
      float q1 = xr[512 + 5*c + 1];
      float q2 = xr[512 + 5*c + 2];
      float q3 = xr[512 + 5*c + 3];
      float q4 = xr[512 + 5*c + 4];
      float rr[5];
#pragma unroll
      for (int i = 0; i < 5; ++i)
        rr[i] = fmaf(d2[0*5+i], q0, fmaf(d2[1*5+i], q1, fmaf(d2[2*5+i], q2,
                 fmaf(d2[3*5+i], q3, d2[4*5+i]*q4))));

      char* Ub = (char*)Uls + el*2048;
      const int ex = (el & 7);
      auto put = [&](int v, float val) {
        *(_Float16*)(Ub + ((((v>>3) ^ ex)<<4) | ((v&7)<<1))) = (_Float16)val;
      };
      put(c, r1);                      // l1 mid
      put(256 + 2*c, r0);              // l1 m1 minus
      put(257 + 2*c, r2);              // l1 m1 plus
      put(128 + c, rr[2]);             // l2 mid
      put(512 + 2*c, rr[1]);           // l2 m1 minus
      put(513 + 2*c, rr[3]);           // l2 m1 plus
      if (c < 64) { put(768 + 2*c, rr[0]);        put(769 + 2*c, rr[4]); }
      else        { put(896 + 2*(c-64), rr[0]);   put(897 + 2*(c-64), rr[4]); }
    }
  }
  __syncthreads();

  // ---- phase 2: 9 section-jobs ----
  const int w = t >> 6, l = t & 63;
  const int wr = w >> 2, wc = w & 3;     // 2 x 4 wave grid over 64 x 128 tile
  const int fr = l & 15, g0 = l >> 4;
  const int sprime = (l & 7) ^ (l >> 3); // B-stage source seg swizzle
  const int rl = l >> 3;

#pragma unroll 1
  for (int j = 0; j < 9; ++j) {
    int K, Aoff, Coff, colBase;
    const _Float16* Mp;
    const float* bias = nullptr;
    if (j < 3)      { K = 256; Aoff = 0;   Coff = 0;   colBase = j*128;     Mp = M0; bias = B0; }
    else if (j < 7) { K = 512; Aoff = 256; Coff = 384; colBase = (j-3)*128; Mp = M1; }
    else            { K = 256; Aoff = 768; Coff = 896; colBase = (j-7)*128; Mp = M2; }

    const char* Bg = (const char*)(Mp + (size_t)colBase*K);

    f32x4 acc[2][2];
#pragma unroll
    for (int m = 0; m < 2; ++m)
#pragma unroll
      for (int nn = 0; nn < 2; ++nn) { f32x4 z = {0.f,0.f,0.f,0.f}; acc[m][nn] = z; }

    for (int kk = 0; kk < K; kk += 64) {
#pragma unroll
      for (int cc = 0; cc < 2; ++cc) {
        const int ch = w*2 + cc;               // B chunk 0..15 (1 KB each)
        const int r = ch*8 + rl;               // B col 0..127
        __builtin_amdgcn_global_load_lds(
            (const AS1 void*)(Bg + (size_t)r*(size_t)(K*2) + (size_t)kk*2 + sprime*16),
            (AS3 void*)((char*)Bls + ch*1024), 16, 0, 0);
      }
      __syncthreads();

#pragma unroll
      for (int h = 0; h < 2; ++h) {
        const int sidx = h*4 + g0;             // K-seg within 64-col tile
        const int gseg = ((Aoff + kk) >> 3) + sidx;
        f16x8 af[2], bf[2];
#pragma unroll
        for (int m = 0; m < 2; ++m) {
          const int row = wr*32 + m*16 + fr;
          af[m] = *(const f16x8*)((const char*)Uls + row*2048 + ((gseg ^ (row & 7))<<4));
        }
#pragma unroll
        for (int nn = 0; nn < 2; ++nn) {
          const int col = wc*32 + nn*16 + fr;
          bf[nn] = *(const f16x8*)((const char*)Bls + col*128 + ((sidx ^ (col & 7))*16));
        }
#pragma unroll
        for (int m = 0; m < 2; ++m)
#pragma unroll
          for (int nn = 0; nn < 2; ++nn)
            acc[m][nn] = __builtin_amdgcn_mfma_f32_16x16x32_f16(af[m], bf[nn], acc[m][nn], 0, 0, 0);
      }
      __syncthreads();
    }

    // epilogue: C/D layout col=l&15, row=(l>>4)*4+j
    float bv[2];
#pragma unroll
    for (int nn = 0; nn < 2; ++nn)
      bv[nn] = bias ? bias[colBase + wc*32 + nn*16 + fr] : 0.f;
#pragma unroll
    for (int m = 0; m < 2; ++m) {
      const int row0 = rowBase + wr*32 + m*16 + g0*4;
#pragma unroll
      for (int nn = 0; nn < 2; ++nn) {
        const int vc = Coff + colBase + wc*32 + nn*16 + fr;
#pragma unroll
        for (int jj = 0; jj < 4; ++jj)
          C[(size_t)(row0 + jj)*1152 + vc] = (_Float16)(acc[m][nn][jj] + bv[nn]);
      }
    }
  }
}

// LDS-free rotate-back: V (f16, ws) -> final f32 layout in d_out.
__global__ __launch_bounds__(256) void rotate_back2(const _Float16* __restrict__ V,
                                                    float* __restrict__ out,
                                                    const float* __restrict__ D1buf,
                                                    const float* __restrict__ D2buf, int n) {
  const int tid = blockIdx.x*256 + threadIdx.x;
  const int e = tid >> 7;
  const int c = tid & 127;
  if (e >= n) return;

  float d1[9], d2[25];
#pragma unroll
  for (int i = 0; i < 9; ++i) d1[i] = D1buf[(size_t)e*9 + i];
#pragma unroll
  for (int i = 0; i < 25; ++i) d2[i] = D2buf[(size_t)e*25 + i];

  const _Float16* Vr = V + (size_t)e*1152;
  float* orow = out + (size_t)e*1152;

  // l=0 passthrough
  orow[c] = (float)Vr[c];

  // l=1: vec = [m1-minus, mid, m1-plus]; o_i = sum_j D1[i,j] p_j
  f16x2 pp = *(const f16x2*)&Vr[384 + 2*c];
  float p0 = (float)pp[0], p2 = (float)pp[1];
  float p1 = (float)Vr[128 + c];
  orow[128 + 3*c + 0] = fmaf(d1[0], p0, fmaf(d1[1], p1, d1[2]*p2));
  orow[128 + 3*c + 1] = fmaf(d1[3], p0, fmaf(d1[4], p1, d1[5]*p2));
  orow[128 + 3*c + 2] = fmaf(d1[6], p0, fmaf(d1[7], p1, d1[8]*p2));

  // l=2: vec = [m2-minus, m1-minus, mid, m1-plus, m2-plus]
  f16x2 qq = (c < 64) ? *(const f16x2*)&Vr[896 + 2*c]
                      : *(const f16x2*)&Vr[1024 + 2*(c-64)];
  float q0 = (float)qq[0], q4 = (float)qq[1];
  f16x2 q13 = *(const f16x2*)&Vr[640 + 2*c];
  float q1 = (float)q13[0], q3 = (float)q13[1];
  float q2 = (float)Vr[256 + c];
#pragma unroll
  for (int i = 0; i < 5; ++i)
    orow[512 + 5*c + i] = fmaf(d2[i*5+0], q0, fmaf(d2[i*5+1], q1, fmaf(d2[i*5+2], q2,
                           fmaf(d2[i*5+3], q3, d2[i*5+4]*q4))));
}

extern "C" void kernel_launch(void* const* d_in, const int* in_sizes, int n_in,
                              void* d_out, int out_size, void* d_ws, size_t ws_size,
                              hipStream_t stream) {
  const float* x  = (const float*)d_in[0];
  const float* R  = (const float*)d_in[1];
  const float* W0 = (const float*)d_in[2];
  const float* b0 = (const float*)d_in[3];
  const float* W1 = (const float*)d_in[4];
  const float* W2 = (const float*)d_in[5];
  float* out = (float*)d_out;

  const int n = in_sizes[0] / 1152;   // 32768

  // ws layout (bytes, 16B-aligned); total ~81 MB
  char* p = (char*)d_ws;
  _Float16* V16 = (_Float16*)p;  p += (size_t)n*1152*2;   // 75.5 MB
  float* D1buf  = (float*)p;     p += (size_t)n*9*4;
  float* D2buf  = (float*)p;     p += (size_t)n*25*4;
  _Float16* M0h = (_Float16*)p;  p += 196608;
  _Float16* M1h = (_Float16*)p;  p += 524288;
  _Float16* M2h = (_Float16*)p;  p += 131072;
  float* B0f    = (float*)p;

  wigner_k<<<(n + 255)/256, 256, 0, stream>>>(R, D1buf, D2buf, n);
  build_mats<<<(426368 + 255)/256, 256, 0, stream>>>(W0, b0, W1, W2, M0h, B0f, M1h, M2h);
  rg_gemm<<<n/64, 512, 0, stream>>>(x, D1buf, D2buf, M0h, B0f, M1h, M2h, V16, n);
  rotate_back2<<<n/2, 256, 0, stream>>>(V16, out, D1buf, D2buf, n);
}